// Round 2
// baseline (1600.550 us; speedup 1.0000x reference)
//
#include <hip/hip_runtime.h>
#include <hip/hip_bf16.h>
#include <math.h>

// RETAIN layer: B=256, T=512, D=128. fp32.
// Path A (ws >= 470MB): proj GEMM -> xp ws, then GRU, then attn (3 kernels).
// Path B (ws >= 67.6MB): fused GRU (x@W computed in-loop), scratch = hB fp32 + e.
// Path C (ws >= 34.1MB): fused GRU with bf16 hB.
// rocprof kernel names reveal which path ran (ws_size oracle).

#define BATCH 256
#define TLEN  512
#define DDIM  128
#define G3    384

static const size_t XP_SZ = (size_t)TLEN * BATCH * G3;    // per-GRU xp floats
static const size_t HB_SZ = (size_t)BATCH * TLEN * DDIM;  // h-state elements
static const size_t E_SZ  = (size_t)BATCH * TLEN;

__device__ __forceinline__ int clamp_len(int l) {
    return l < 1 ? 1 : (l > TLEN ? TLEN : l);
}

template<bool BF16>
__device__ __forceinline__ float loadH(const void* p, size_t i) {
    if constexpr (BF16) return __bfloat162float(((const __hip_bfloat16*)p)[i]);
    else return ((const float*)p)[i];
}

// ---------------- Path A 1) projection: xp[t,b,:] = rx[b,t,:] @ W + b_in ----------------
// grid = 2 * B * (T/32) = 8192, block = 384 (thread j owns output column j for 32 t-rows)
__global__ __launch_bounds__(384) void retain_proj(
    const float* __restrict__ x, const int* __restrict__ lengths,
    const float* __restrict__ Wa, const float* __restrict__ ba_in,
    const float* __restrict__ Wb, const float* __restrict__ bb_in,
    float* __restrict__ xpbase)
{
    const int bid  = blockIdx.x;
    const int tile = bid & 15;
    const int b    = (bid >> 4) & 255;
    const int g    = bid >> 12;
    const int len  = clamp_len(lengths[b]);
    const int t0   = tile * 32;
    if (t0 >= len) return;

    const float* __restrict__ W  = g ? Wb : Wa;
    const float* __restrict__ bi = g ? bb_in : ba_in;
    float* __restrict__ xp = xpbase + (size_t)g * XP_SZ;

    __shared__ float rx[32 * 128];
    const int tid = threadIdx.x;
    for (int idx = tid; idx < 32 * 128; idx += 384) {
        const int row = idx >> 7, d = idx & 127;
        const int t = t0 + row;
        float v = 0.f;
        if (t < len) v = x[((size_t)b * TLEN + (len - 1 - t)) * DDIM + d];
        rx[idx] = v;
    }
    __syncthreads();

    const int j = tid;
    float acc[32];
    #pragma unroll
    for (int i = 0; i < 32; i++) acc[i] = 0.f;

    for (int r = 0; r < 128; r += 4) {
        const float w0 = W[(r + 0) * G3 + j];
        const float w1 = W[(r + 1) * G3 + j];
        const float w2 = W[(r + 2) * G3 + j];
        const float w3 = W[(r + 3) * G3 + j];
        #pragma unroll
        for (int row = 0; row < 32; row++) {
            const float4 h4 = *reinterpret_cast<const float4*>(&rx[row * 128 + r]);
            acc[row] = fmaf(h4.x, w0, acc[row]);
            acc[row] = fmaf(h4.y, w1, acc[row]);
            acc[row] = fmaf(h4.z, w2, acc[row]);
            acc[row] = fmaf(h4.w, w3, acc[row]);
        }
    }

    const float bj = bi[j];
    const int nrows = min(32, len - t0);
    #pragma unroll
    for (int row = 0; row < 32; row++) {
        if (row < nrows) {
            const int t = t0 + row;
            xp[((size_t)t * BATCH + b) * G3 + j] = acc[row] + bj;
        }
    }
}

// ---------------- Path A 2) GRU recurrence (precomputed xp) ----------------
__global__ __launch_bounds__(768, 3) void retain_gru(
    const float* __restrict__ Ua, const float* __restrict__ ba_rec,
    const float* __restrict__ Ub, const float* __restrict__ bb_rec,
    const float* __restrict__ W_alpha, const float* __restrict__ b_alpha,
    const int* __restrict__ lengths, const float* __restrict__ xpbase,
    float* __restrict__ hB, float* __restrict__ e)
{
    const int bid = blockIdx.x;
    const int b   = bid & 255;
    const int g   = bid >> 8;
    const int len = clamp_len(lengths[b]);

    const float* __restrict__ U  = g ? Ub : Ua;
    const float* __restrict__ br = g ? bb_rec : ba_rec;
    const float* __restrict__ xp = xpbase + (size_t)g * XP_SZ;

    const int tid  = threadIdx.x;
    const int half = (tid >= 384) ? 1 : 0;
    const int j    = half ? tid - 384 : tid;

    float Ureg[64];
    #pragma unroll
    for (int rr = 0; rr < 64; rr++) Ureg[rr] = U[(half * 64 + rr) * G3 + j];
    const float accInit = half ? 0.f : br[j];

    __shared__ float hsh[128];
    __shared__ float part[2][384];
    __shared__ float sred[2];
    if (tid < 128) hsh[tid] = 0.f;

    float xz = 0.f, xr = 0.f, xh = 0.f, wal = 0.f, balv = 0.f;
    if (tid < 128) {
        wal  = W_alpha[tid];
        balv = b_alpha[0];
        const float* xpt = xp + (size_t)b * G3;   // t = 0
        xz = xpt[tid]; xr = xpt[128 + tid]; xh = xpt[256 + tid];
    }
    __syncthreads();

    for (int t = 0; t < len; t++) {
        float a0 = accInit, a1 = 0.f;
        #pragma unroll
        for (int rr = 0; rr < 64; rr += 4) {
            const float4 h4 = *reinterpret_cast<const float4*>(&hsh[half * 64 + rr]);
            a0 = fmaf(h4.x, Ureg[rr + 0], a0);
            a1 = fmaf(h4.y, Ureg[rr + 1], a1);
            a0 = fmaf(h4.z, Ureg[rr + 2], a0);
            a1 = fmaf(h4.w, Ureg[rr + 3], a1);
        }
        part[half][j] = a0 + a1;
        __syncthreads();

        if (tid < 128) {
            const int d = tid;
            const float rz  = part[0][d]       + part[1][d];
            const float rr_ = part[0][128 + d] + part[1][128 + d];
            const float rh  = part[0][256 + d] + part[1][256 + d];
            const float z  = 1.f / (1.f + expf(-(xz + rz)));
            const float rg = 1.f / (1.f + expf(-(xr + rr_)));
            const float hh = tanhf(xh + rg * rh);
            const float hn = z * hsh[d] + (1.f - z) * hh;
            hsh[d] = hn;
            if (g) {
                hB[((size_t)b * TLEN + t) * DDIM + d] = hn;
            } else {
                float pa = hn * wal;
                #pragma unroll
                for (int off = 32; off > 0; off >>= 1) pa += __shfl_down(pa, off);
                if ((tid & 63) == 0) sred[tid >> 6] = pa;
            }
            const int tn = (t + 1 < len) ? t + 1 : len - 1;
            const float* xpt = xp + ((size_t)tn * BATCH + b) * G3;
            xz = xpt[d]; xr = xpt[128 + d]; xh = xpt[256 + d];
        }
        __syncthreads();
        if (!g && tid == 0) e[(size_t)b * TLEN + t] = sred[0] + sred[1] + balv;
    }
}

// ---------------- Path B/C: fused GRU (x@W in-loop, no xp scratch) ----------------
// grid = 512 (g = bid>>8, b = bid&255), block = 768. Thread owns column j, 64-row slice.
template<bool STORE_BF16>
__global__ __launch_bounds__(768, 3) void retain_gru_fused(
    const float* __restrict__ x, const int* __restrict__ lengths,
    const float* __restrict__ Wa, const float* __restrict__ Ua,
    const float* __restrict__ ba_in, const float* __restrict__ ba_rec,
    const float* __restrict__ Wb, const float* __restrict__ Ub,
    const float* __restrict__ bb_in, const float* __restrict__ bb_rec,
    const float* __restrict__ W_alpha, const float* __restrict__ b_alpha,
    void* __restrict__ hBv, float* __restrict__ e)
{
    const int bid = blockIdx.x;
    const int b   = bid & 255;
    const int g   = bid >> 8;
    const int len = clamp_len(lengths[b]);

    const float* __restrict__ W  = g ? Wb : Wa;
    const float* __restrict__ U  = g ? Ub : Ua;
    const float* __restrict__ bi = g ? bb_in : ba_in;
    const float* __restrict__ br = g ? bb_rec : ba_rec;

    const int tid  = threadIdx.x;
    const int half = (tid >= 384) ? 1 : 0;
    const int j    = half ? tid - 384 : tid;

    float Wreg[64], Ureg[64];
    #pragma unroll
    for (int rr = 0; rr < 64; rr++) {
        Wreg[rr] = W[(half * 64 + rr) * G3 + j];
        Ureg[rr] = U[(half * 64 + rr) * G3 + j];
    }
    const float axInit = half ? 0.f : bi[j];
    const float auInit = half ? 0.f : br[j];

    __shared__ float xsh[2][128];
    __shared__ float hsh[128];
    __shared__ float partX[2][384];
    __shared__ float partU[2][384];
    __shared__ float sred[2];

    float wal = 0.f, balv = 0.f;
    if (tid < 128) {
        hsh[tid] = 0.f;
        xsh[0][tid] = x[((size_t)b * TLEN + (len - 1)) * DDIM + tid];  // rx row t=0
        wal  = W_alpha[tid];
        balv = b_alpha[0];
    }
    __syncthreads();

    for (int t = 0; t < len; t++) {
        // issue next reversed-x row load early; latency hides under the matvec
        float xnext = 0.f;
        if (tid < 128) {
            int rn = len - 2 - t; if (rn < 0) rn = 0;
            xnext = x[((size_t)b * TLEN + rn) * DDIM + tid];
        }
        const int cur = t & 1;
        float ax = axInit, au = auInit;
        #pragma unroll
        for (int rr = 0; rr < 64; rr += 4) {
            const float4 xv = *reinterpret_cast<const float4*>(&xsh[cur][half * 64 + rr]);
            const float4 hv = *reinterpret_cast<const float4*>(&hsh[half * 64 + rr]);
            ax = fmaf(xv.x, Wreg[rr + 0], ax); au = fmaf(hv.x, Ureg[rr + 0], au);
            ax = fmaf(xv.y, Wreg[rr + 1], ax); au = fmaf(hv.y, Ureg[rr + 1], au);
            ax = fmaf(xv.z, Wreg[rr + 2], ax); au = fmaf(hv.z, Ureg[rr + 2], au);
            ax = fmaf(xv.w, Wreg[rr + 3], ax); au = fmaf(hv.w, Ureg[rr + 3], au);
        }
        partX[half][j] = ax;
        partU[half][j] = au;
        __syncthreads();

        if (tid < 128) {
            const int d = tid;
            const float xz = partX[0][d]       + partX[1][d];
            const float xr = partX[0][128 + d] + partX[1][128 + d];
            const float xh = partX[0][256 + d] + partX[1][256 + d];
            const float rz  = partU[0][d]       + partU[1][d];
            const float rr_ = partU[0][128 + d] + partU[1][128 + d];
            const float rh  = partU[0][256 + d] + partU[1][256 + d];
            const float z  = 1.f / (1.f + expf(-(xz + rz)));
            const float rg = 1.f / (1.f + expf(-(xr + rr_)));
            const float hh = tanhf(xh + rg * rh);
            const float hn = z * hsh[d] + (1.f - z) * hh;
            hsh[d] = hn;
            xsh[cur ^ 1][d] = xnext;
            if (g) {
                const size_t oi = ((size_t)b * TLEN + t) * DDIM + d;
                if constexpr (STORE_BF16) ((__hip_bfloat16*)hBv)[oi] = __float2bfloat16(hn);
                else                      ((float*)hBv)[oi] = hn;
            } else {
                float pa = hn * wal;
                #pragma unroll
                for (int off = 32; off > 0; off >>= 1) pa += __shfl_down(pa, off);
                if ((tid & 63) == 0) sred[tid >> 6] = pa;
            }
        }
        __syncthreads();
        if (!g && tid == 0) e[(size_t)b * TLEN + t] = sred[0] + sred[1] + balv;
    }
}

// ---------------- attn: softmax(e) + tanh(h@Wbeta) + weighted sum ----------------
// grid = 512 (2 blocks per b), block = 256 (d = tid&127, rh = tid>>7)
template<bool HB_BF16>
__global__ __launch_bounds__(256) void retain_attn(
    const float* __restrict__ x, const int* __restrict__ lengths,
    const float* __restrict__ W_beta, const float* __restrict__ b_beta,
    const void* __restrict__ hBv, const float* __restrict__ eb,
    float* __restrict__ out)
{
    const int bid   = blockIdx.x;
    const int b     = bid >> 1;
    const int thalf = bid & 1;
    const int len   = clamp_len(lengths[b]);
    const float* __restrict__ e = eb + (size_t)b * TLEN;

    const int tid = threadIdx.x;
    const int d   = tid & 127;
    const int rh  = tid >> 7;

    float Wreg[64];
    #pragma unroll
    for (int rr = 0; rr < 64; rr++) Wreg[rr] = W_beta[(rh * 64 + rr) * DDIM + d];
    const float bb = b_beta[d];

    __shared__ float se[512];
    __shared__ float red[256];
    __shared__ float h2[2][128];
    __shared__ float part[2][2][128];

    for (int idx = tid; idx < 512; idx += 256) {
        const int tc = idx < len ? idx : len - 1;  // mask carry-forward
        se[idx] = e[tc];
    }
    __syncthreads();
    red[tid] = fmaxf(se[tid], se[tid + 256]);
    __syncthreads();
    for (int s = 128; s > 0; s >>= 1) {
        if (tid < s) red[tid] = fmaxf(red[tid], red[tid + s]);
        __syncthreads();
    }
    const float mx = red[0];
    __syncthreads();
    const float s0 = expf(se[tid] - mx), s1 = expf(se[tid + 256] - mx);
    se[tid] = s0; se[tid + 256] = s1;
    red[tid] = s0 + s1;
    __syncthreads();
    for (int s = 128; s > 0; s >>= 1) {
        if (tid < s) red[tid] += red[tid + s];
        __syncthreads();
    }
    const float inv = 1.f / red[0];
    __syncthreads();

    const int tbase = thalf * 256;
    float acc = 0.f;
    for (int tp = 0; tp < 256; tp += 2) {
        const int t0 = tbase + tp;
        {
            const int t  = t0 + rh;
            const int tc = t < len ? t : len - 1;
            h2[rh][d] = loadH<HB_BF16>(hBv, ((size_t)b * TLEN + tc) * DDIM + d);
        }
        __syncthreads();
        float p0 = 0.f, p1 = 0.f;
        #pragma unroll
        for (int rr = 0; rr < 64; rr += 4) {
            const float4 ha = *reinterpret_cast<const float4*>(&h2[0][rh * 64 + rr]);
            const float4 hb = *reinterpret_cast<const float4*>(&h2[1][rh * 64 + rr]);
            p0 = fmaf(ha.x, Wreg[rr + 0], p0);
            p0 = fmaf(ha.y, Wreg[rr + 1], p0);
            p0 = fmaf(ha.z, Wreg[rr + 2], p0);
            p0 = fmaf(ha.w, Wreg[rr + 3], p0);
            p1 = fmaf(hb.x, Wreg[rr + 0], p1);
            p1 = fmaf(hb.y, Wreg[rr + 1], p1);
            p1 = fmaf(hb.z, Wreg[rr + 2], p1);
            p1 = fmaf(hb.w, Wreg[rr + 3], p1);
        }
        part[rh][0][d] = p0;
        part[rh][1][d] = p1;
        __syncthreads();
        if (rh == 0) {
            #pragma unroll
            for (int ti = 0; ti < 2; ti++) {
                const int t = t0 + ti;
                const float v  = tanhf(part[0][ti][d] + part[1][ti][d] + bb);
                const float al = se[t] * inv;
                const float xv = x[((size_t)b * TLEN + t) * DDIM + d];
                acc = fmaf(al * v, xv, acc);
            }
        }
        __syncthreads();
    }
    if (rh == 0) atomicAdd(&out[b * DDIM + d], acc);
}

extern "C" void kernel_launch(void* const* d_in, const int* in_sizes, int n_in,
                              void* d_out, int out_size, void* d_ws, size_t ws_size,
                              hipStream_t stream)
{
    const float* x       = (const float*)d_in[0];
    const int*   lengths = (const int*)  d_in[1];
    const float* Wa      = (const float*)d_in[2];
    const float* Ua      = (const float*)d_in[3];
    const float* ba_in   = (const float*)d_in[4];
    const float* ba_rec  = (const float*)d_in[5];
    const float* Wb      = (const float*)d_in[6];
    const float* Ub      = (const float*)d_in[7];
    const float* bb_in   = (const float*)d_in[8];
    const float* bb_rec  = (const float*)d_in[9];
    const float* W_alpha = (const float*)d_in[10];
    const float* b_alpha = (const float*)d_in[11];
    const float* W_beta  = (const float*)d_in[12];
    const float* b_beta  = (const float*)d_in[13];
    float* out = (float*)d_out;
    float* ws  = (float*)d_ws;

    const size_t need_big  = (2 * XP_SZ + HB_SZ + E_SZ) * sizeof(float);   // ~470 MB
    const size_t need_f32  = (HB_SZ + E_SZ) * sizeof(float);               // ~67.6 MB
    const size_t need_bf16 = HB_SZ * 2 + E_SZ * sizeof(float);             // ~34.1 MB

    hipMemsetAsync(d_out, 0, (size_t)out_size * sizeof(float), stream);

    if (ws_size >= need_big) {
        float* xp = ws;
        float* hB = ws + 2 * XP_SZ;
        float* e  = hB + HB_SZ;
        retain_proj<<<8192, 384, 0, stream>>>(x, lengths, Wa, ba_in, Wb, bb_in, xp);
        retain_gru <<<512,  768, 0, stream>>>(Ua, ba_rec, Ub, bb_rec, W_alpha, b_alpha,
                                              lengths, xp, hB, e);
        retain_attn<false><<<512, 256, 0, stream>>>(x, lengths, W_beta, b_beta, hB, e, out);
    } else if (ws_size >= need_f32) {
        float* hB = ws;
        float* e  = ws + HB_SZ;
        retain_gru_fused<false><<<512, 768, 0, stream>>>(
            x, lengths, Wa, Ua, ba_in, ba_rec, Wb, Ub, bb_in, bb_rec, W_alpha, b_alpha, hB, e);
        retain_attn<false><<<512, 256, 0, stream>>>(x, lengths, W_beta, b_beta, hB, e, out);
    } else if (ws_size >= need_bf16) {
        void*  hB = (void*)ws;
        float* e  = (float*)((char*)d_ws + HB_SZ * 2);
        retain_gru_fused<true><<<512, 768, 0, stream>>>(
            x, lengths, Wa, Ua, ba_in, ba_rec, Wb, Ub, bb_in, bb_rec, W_alpha, b_alpha, hB, e);
        retain_attn<true><<<512, 256, 0, stream>>>(x, lengths, W_beta, b_beta, hB, e, out);
    }
    // ws < 34 MB: nothing launched -> absmax == max|ref| signals the bracket
}

// Round 4
// 1031.821 us; speedup vs baseline: 1.5512x; 1.5512x over previous
//
#include <hip/hip_runtime.h>
#include <hip/hip_bf16.h>
#include <math.h>

// RETAIN layer: B=256, T=512, D=128. fp32.
// retain_gru_persist: 256 blocks (1/CU), block = 512 threads.
//   - blockIdx & 1 = which GRU (g), blockIdx >> 1 = pair index.
//   - Each block rank-sorts lengths in LDS and processes jobs sorted[i] and
//     sorted[255-i] sequentially -> every block runs ~513 steps (balanced).
//   - Thread owns 3 column-dots x 64 rows of W (tid<256) or U (tid>=256):
//     192 weight floats in VGPRs; x/h broadcast from LDS, 1 b128 read feeds
//     12 FMAs (3x fewer LDS insts than round-2 kernel, which was LDS-bound).
// retain_attn: unchanged from passing round-2 kernel.
// ws: hB [B][T][128] fp32 (or bf16 fallback), e [B][T] fp32.

#define BATCH 256
#define TLEN  512
#define DDIM  128
#define G3    384

static const size_t HB_SZ = (size_t)BATCH * TLEN * DDIM;
static const size_t E_SZ  = (size_t)BATCH * TLEN;

__device__ __forceinline__ int clamp_len(int l) {
    return l < 1 ? 1 : (l > TLEN ? TLEN : l);
}

__device__ __forceinline__ float sigm_f(float s) {
    s = fminf(fmaxf(s, -30.f), 30.f);
    return __fdividef(1.f, 1.f + __expf(-s));
}
__device__ __forceinline__ float tanh_f(float u) {
    u = fminf(fmaxf(u, -15.f), 15.f);
    const float e2 = __expf(2.f * u);
    return __fdividef(e2 - 1.f, e2 + 1.f);
}

template<bool BF16>
__device__ __forceinline__ float loadH(const void* p, size_t i) {
    if constexpr (BF16) return __bfloat162float(((const __hip_bfloat16*)p)[i]);
    else return ((const float*)p)[i];
}

// ---------------- persistent length-balanced fused GRU ----------------
template<bool STORE_BF16>
__global__ __launch_bounds__(512, 2) void retain_gru_persist(
    const float* __restrict__ x, const int* __restrict__ lengths,
    const float* __restrict__ Wa, const float* __restrict__ Ua,
    const float* __restrict__ ba_in, const float* __restrict__ ba_rec,
    const float* __restrict__ Wb, const float* __restrict__ Ub,
    const float* __restrict__ bb_in, const float* __restrict__ bb_rec,
    const float* __restrict__ W_alpha, const float* __restrict__ b_alpha,
    void* __restrict__ hBv, float* __restrict__ e)
{
    const int g  = blockIdx.x & 1;
    const int ip = blockIdx.x >> 1;          // 0..127

    const int tid  = threadIdx.x;
    const int isU  = tid >= 256;             // wave-uniform
    const int tt   = tid & 255;
    const int half = tt >> 7;                // wave-uniform (64-aligned)
    const int c    = tt & 127;

    __shared__ int lensh[BATCH];
    __shared__ int rank2b[BATCH];
    __shared__ __align__(16) float xsh[2][DDIM];
    __shared__ __align__(16) float hsh[DDIM];
    __shared__ float partX[2][G3];
    __shared__ float partU[2][G3];
    __shared__ float sred[2];

    if (tid < BATCH) lensh[tid] = clamp_len(lengths[tid]);
    __syncthreads();
    if (tid < BATCH) {                        // rank-sort (descending, stable)
        const int myl = lensh[tid];
        int rank = 0;
        for (int j = 0; j < BATCH; ++j) {
            const int lj = lensh[j];
            rank += (lj > myl) || (lj == myl && j < tid);
        }
        rank2b[rank] = tid;
    }

    // ---- weights into registers: 3 columns x 64 rows ----
    const float* __restrict__ M = isU ? (g ? Ub : Ua) : (g ? Wb : Wa);
    float Wr0[64], Wr1[64], Wr2[64];
    #pragma unroll
    for (int r = 0; r < 64; ++r) {
        const float* row = M + (size_t)(half * 64 + r) * G3 + c;
        Wr0[r] = row[0]; Wr1[r] = row[128]; Wr2[r] = row[256];
    }
    const float* __restrict__ bias = isU ? (g ? bb_rec : ba_rec) : (g ? bb_in : ba_in);
    const float i0 = half ? 0.f : bias[c];
    const float i1 = half ? 0.f : bias[c + 128];
    const float i2 = half ? 0.f : bias[c + 256];

    float wal = 0.f, balv = 0.f;
    if (tid < DDIM) { wal = W_alpha[tid]; balv = b_alpha[0]; }
    __syncthreads();                          // rank2b ready

    for (int jj = 0; jj < 2; ++jj) {
        const int b   = rank2b[jj == 0 ? ip : (255 - ip)];
        const int len = lensh[b];

        if (tid < DDIM) {
            hsh[tid] = 0.f;
            xsh[0][tid] = x[((size_t)b * TLEN + (len - 1)) * DDIM + tid];
        }
        __syncthreads();

        for (int t = 0; t < len; ++t) {
            float xnext = 0.f;
            if (tid < DDIM) {                 // prefetch next reversed row
                int rn = len - 2 - t; if (rn < 0) rn = 0;
                xnext = x[((size_t)b * TLEN + rn) * DDIM + tid];
            }

            const float* __restrict__ vh =
                (isU ? hsh : xsh[t & 1]) + half * 64;   // wave-uniform addr
            float a0 = i0, a1 = i1, a2 = i2;
            float c0 = 0.f, c1 = 0.f, c2 = 0.f;
            #pragma unroll
            for (int rr = 0; rr < 32; rr += 4) {
                const float4 v = *reinterpret_cast<const float4*>(vh + rr);
                a0 = fmaf(v.x, Wr0[rr+0], a0); a1 = fmaf(v.x, Wr1[rr+0], a1); a2 = fmaf(v.x, Wr2[rr+0], a2);
                a0 = fmaf(v.y, Wr0[rr+1], a0); a1 = fmaf(v.y, Wr1[rr+1], a1); a2 = fmaf(v.y, Wr2[rr+1], a2);
                a0 = fmaf(v.z, Wr0[rr+2], a0); a1 = fmaf(v.z, Wr1[rr+2], a1); a2 = fmaf(v.z, Wr2[rr+2], a2);
                a0 = fmaf(v.w, Wr0[rr+3], a0); a1 = fmaf(v.w, Wr1[rr+3], a1); a2 = fmaf(v.w, Wr2[rr+3], a2);
            }
            #pragma unroll
            for (int rr = 32; rr < 64; rr += 4) {
                const float4 v = *reinterpret_cast<const float4*>(vh + rr);
                c0 = fmaf(v.x, Wr0[rr+0], c0); c1 = fmaf(v.x, Wr1[rr+0], c1); c2 = fmaf(v.x, Wr2[rr+0], c2);
                c0 = fmaf(v.y, Wr0[rr+1], c0); c1 = fmaf(v.y, Wr1[rr+1], c1); c2 = fmaf(v.y, Wr2[rr+1], c2);
                c0 = fmaf(v.z, Wr0[rr+2], c0); c1 = fmaf(v.z, Wr1[rr+2], c1); c2 = fmaf(v.z, Wr2[rr+2], c2);
                c0 = fmaf(v.w, Wr0[rr+3], c0); c1 = fmaf(v.w, Wr1[rr+3], c1); c2 = fmaf(v.w, Wr2[rr+3], c2);
            }
            float* __restrict__ P = isU ? partU[half] : partX[half];
            P[c] = a0 + c0; P[c + 128] = a1 + c1; P[c + 256] = a2 + c2;
            __syncthreads();

            if (tid < DDIM) {
                const int d = tid;
                const float xz = partX[0][d]       + partX[1][d];
                const float xr = partX[0][128 + d] + partX[1][128 + d];
                const float xh = partX[0][256 + d] + partX[1][256 + d];
                const float rz  = partU[0][d]       + partU[1][d];
                const float rr_ = partU[0][128 + d] + partU[1][128 + d];
                const float rh  = partU[0][256 + d] + partU[1][256 + d];
                const float z  = sigm_f(xz + rz);
                const float rg = sigm_f(xr + rr_);
                const float hh = tanh_f(xh + rg * rh);
                const float hn = z * hsh[d] + (1.f - z) * hh;
                hsh[d] = hn;
                xsh[(t & 1) ^ 1][d] = xnext;
                if (g) {
                    const size_t oi = ((size_t)b * TLEN + t) * DDIM + d;
                    if constexpr (STORE_BF16) ((__hip_bfloat16*)hBv)[oi] = __float2bfloat16(hn);
                    else                      ((float*)hBv)[oi] = hn;
                } else {
                    float pa = hn * wal;
                    #pragma unroll
                    for (int off = 32; off > 0; off >>= 1) pa += __shfl_down(pa, off);
                    if ((tid & 63) == 0) sred[tid >> 6] = pa;
                }
            }
            __syncthreads();
            if (!g && tid == 0) e[(size_t)b * TLEN + t] = sred[0] + sred[1] + balv;
        }
        __syncthreads();                      // job boundary
    }
}

// ---------------- attn: softmax(e) + tanh(h@Wbeta) + weighted sum ----------------
// grid = 512 (2 blocks per b), block = 256 (d = tid&127, rh = tid>>7)
template<bool HB_BF16>
__global__ __launch_bounds__(256) void retain_attn(
    const float* __restrict__ x, const int* __restrict__ lengths,
    const float* __restrict__ W_beta, const float* __restrict__ b_beta,
    const void* __restrict__ hBv, const float* __restrict__ eb,
    float* __restrict__ out)
{
    const int bid   = blockIdx.x;
    const int b     = bid >> 1;
    const int thalf = bid & 1;
    const int len   = clamp_len(lengths[b]);
    const float* __restrict__ e = eb + (size_t)b * TLEN;

    const int tid = threadIdx.x;
    const int d   = tid & 127;
    const int rh  = tid >> 7;

    float Wreg[64];
    #pragma unroll
    for (int rr = 0; rr < 64; rr++) Wreg[rr] = W_beta[(rh * 64 + rr) * DDIM + d];
    const float bb = b_beta[d];

    __shared__ float se[512];
    __shared__ float red[256];
    __shared__ __align__(16) float h2[2][128];
    __shared__ float part[2][2][128];

    for (int idx = tid; idx < 512; idx += 256) {
        const int tc = idx < len ? idx : len - 1;  // mask carry-forward
        se[idx] = e[tc];
    }
    __syncthreads();
    red[tid] = fmaxf(se[tid], se[tid + 256]);
    __syncthreads();
    for (int s = 128; s > 0; s >>= 1) {
        if (tid < s) red[tid] = fmaxf(red[tid], red[tid + s]);
        __syncthreads();
    }
    const float mx = red[0];
    __syncthreads();
    const float s0 = expf(se[tid] - mx), s1 = expf(se[tid + 256] - mx);
    se[tid] = s0; se[tid + 256] = s1;
    red[tid] = s0 + s1;
    __syncthreads();
    for (int s = 128; s > 0; s >>= 1) {
        if (tid < s) red[tid] += red[tid + s];
        __syncthreads();
    }
    const float inv = 1.f / red[0];
    __syncthreads();

    const int tbase = thalf * 256;
    float acc = 0.f;
    for (int tp = 0; tp < 256; tp += 2) {
        const int t0 = tbase + tp;
        {
            const int t  = t0 + rh;
            const int tc = t < len ? t : len - 1;
            h2[rh][d] = loadH<HB_BF16>(hBv, ((size_t)b * TLEN + tc) * DDIM + d);
        }
        __syncthreads();
        float p0 = 0.f, p1 = 0.f;
        #pragma unroll
        for (int rr = 0; rr < 64; rr += 4) {
            const float4 ha = *reinterpret_cast<const float4*>(&h2[0][rh * 64 + rr]);
            const float4 hb = *reinterpret_cast<const float4*>(&h2[1][rh * 64 + rr]);
            p0 = fmaf(ha.x, Wreg[rr + 0], p0);
            p0 = fmaf(ha.y, Wreg[rr + 1], p0);
            p0 = fmaf(ha.z, Wreg[rr + 2], p0);
            p0 = fmaf(ha.w, Wreg[rr + 3], p0);
            p1 = fmaf(hb.x, Wreg[rr + 0], p1);
            p1 = fmaf(hb.y, Wreg[rr + 1], p1);
            p1 = fmaf(hb.z, Wreg[rr + 2], p1);
            p1 = fmaf(hb.w, Wreg[rr + 3], p1);
        }
        part[rh][0][d] = p0;
        part[rh][1][d] = p1;
        __syncthreads();
        if (rh == 0) {
            #pragma unroll
            for (int ti = 0; ti < 2; ti++) {
                const int t = t0 + ti;
                const float v  = tanhf(part[0][ti][d] + part[1][ti][d] + bb);
                const float al = se[t] * inv;
                const float xv = x[((size_t)b * TLEN + t) * DDIM + d];
                acc = fmaf(al * v, xv, acc);
            }
        }
        __syncthreads();
    }
    if (rh == 0) atomicAdd(&out[b * DDIM + d], acc);
}

extern "C" void kernel_launch(void* const* d_in, const int* in_sizes, int n_in,
                              void* d_out, int out_size, void* d_ws, size_t ws_size,
                              hipStream_t stream)
{
    const float* x       = (const float*)d_in[0];
    const int*   lengths = (const int*)  d_in[1];
    const float* Wa      = (const float*)d_in[2];
    const float* Ua      = (const float*)d_in[3];
    const float* ba_in   = (const float*)d_in[4];
    const float* ba_rec  = (const float*)d_in[5];
    const float* Wb      = (const float*)d_in[6];
    const float* Ub      = (const float*)d_in[7];
    const float* bb_in   = (const float*)d_in[8];
    const float* bb_rec  = (const float*)d_in[9];
    const float* W_alpha = (const float*)d_in[10];
    const float* b_alpha = (const float*)d_in[11];
    const float* W_beta  = (const float*)d_in[12];
    const float* b_beta  = (const float*)d_in[13];
    float* out = (float*)d_out;
    float* ws  = (float*)d_ws;

    const size_t need_f32  = (HB_SZ + E_SZ) * sizeof(float);   // ~67.6 MB
    const size_t need_bf16 = HB_SZ * 2 + E_SZ * sizeof(float); // ~34.1 MB

    hipMemsetAsync(d_out, 0, (size_t)out_size * sizeof(float), stream);

    if (ws_size >= need_f32) {
        float* hB = ws;
        float* e  = ws + HB_SZ;
        retain_gru_persist<false><<<256, 512, 0, stream>>>(
            x, lengths, Wa, Ua, ba_in, ba_rec, Wb, Ub, bb_in, bb_rec, W_alpha, b_alpha, hB, e);
        retain_attn<false><<<512, 256, 0, stream>>>(x, lengths, W_beta, b_beta, hB, e, out);
    } else if (ws_size >= need_bf16) {
        void*  hB = (void*)ws;
        float* e  = (float*)((char*)d_ws + HB_SZ * 2);
        retain_gru_persist<true><<<256, 512, 0, stream>>>(
            x, lengths, Wa, Ua, ba_in, ba_rec, Wb, Ub, bb_in, bb_rec, W_alpha, b_alpha, hB, e);
        retain_attn<true><<<512, 256, 0, stream>>>(x, lengths, W_beta, b_beta, hB, e, out);
    }
}